// Round 2
// baseline (24.843 us; speedup 1.0000x reference)
//
#include <hip/hip_runtime.h>

// BayesianDiffSizeCatEmbeddings: out[b, off_i : off_i+dim_i] =
//   mu_i[idx,:] + softplus(rho_i[idx,:]) * eps_i[idx,:],  idx = X[b,i]
// 8 tables, dims {64,64,32,32,16,16,16,8}, BATCH=16384, out = [16384, 248] f32.
// Memory-bound gather (~60 MB total). Exact 1D grid: no empty blocks, no guards.

constexpr int BATCH = 16384;
constexpr int NCOLS = 8;
constexpr int OUT_ROW = 248;

struct Params {
    const float* mu[NCOLS];
    const float* rho[NCOLS];
    const float* eps[NCOLS];
    const int*   X;     // [BATCH, 8] int32
    float*       out;   // [BATCH, 248] f32
};

// dims {64,64,32,32,16,16,16,8} -> float4s/row {16,16,8,8,4,4,4,2}
__device__ __constant__ int DSHIFT[NCOLS] = {4, 4, 3, 3, 2, 2, 2, 1};
__device__ __constant__ int COLOFF[NCOLS] = {0, 64, 128, 160, 192, 208, 224, 240};
// blocks per col = (BATCH << dshift) / 256 -> {1024,1024,512,512,256,256,256,128}
__device__ __constant__ int BPREFIX[NCOLS + 1] = {0, 1024, 2048, 2560, 3072, 3328, 3584, 3840, 3968};
constexpr int TOTAL_BLOCKS = 3968;

__device__ __forceinline__ float softplus_f(float x) {
    // jax.nn.softplus = log1p(exp(x)); rho ~ N(-6,0.1) so the guard never fires,
    // kept for exactness.
    return (x > 15.0f) ? x : log1pf(__expf(x));
}

__global__ __launch_bounds__(256) void bayes_embed_kernel(Params p) {
    const int bx = blockIdx.x;

    // block-uniform column select (folds to scalar ops; no divergence)
    int col = 0;
#pragma unroll
    for (int c = 1; c < NCOLS; ++c) col += (bx >= BPREFIX[c]);

    const int dshift = DSHIFT[col];
    const int coff   = COLOFF[col];

    const int t  = (bx - BPREFIX[col]) * 256 + threadIdx.x; // quad id within column
    const int b  = t >> dshift;                             // batch row
    const int d4 = t & ((1 << dshift) - 1);                 // float4 within row

    const int idx = p.X[b * NCOLS + col];

    // 32-bit offsets: max = 1e6 * 64 floats = 6.4e7 << 2^31
    const unsigned base = ((unsigned)idx << (dshift + 2)) + ((unsigned)d4 << 2);
    const float4 m = *(const float4*)(p.mu[col]  + base);
    const float4 r = *(const float4*)(p.rho[col] + base);
    const float4 e = *(const float4*)(p.eps[col] + base);

    float4 o;
    o.x = m.x + softplus_f(r.x) * e.x;
    o.y = m.y + softplus_f(r.y) * e.y;
    o.z = m.z + softplus_f(r.z) * e.z;
    o.w = m.w + softplus_f(r.w) * e.w;

    const unsigned ob = (unsigned)b * OUT_ROW + coff + (d4 << 2);
    *(float4*)(p.out + ob) = o;
}

extern "C" void kernel_launch(void* const* d_in, const int* in_sizes, int n_in,
                              void* d_out, int out_size, void* d_ws, size_t ws_size,
                              hipStream_t stream) {
    Params p;
    for (int i = 0; i < NCOLS; ++i) {
        p.mu[i]  = (const float*)d_in[3 * i + 0];
        p.rho[i] = (const float*)d_in[3 * i + 1];
        p.eps[i] = (const float*)d_in[3 * i + 2];
    }
    p.X   = (const int*)d_in[24];
    p.out = (float*)d_out;

    bayes_embed_kernel<<<dim3(TOTAL_BLOCKS), 256, 0, stream>>>(p);
}

// Round 4
// 19.010 us; speedup vs baseline: 1.3069x; 1.3069x over previous
//
#include <hip/hip_runtime.h>

// BayesianDiffSizeCatEmbeddings: out[b, off_i : off_i+dim_i] =
//   mu_i[idx,:] + softplus(rho_i[idx,:]) * eps_i[idx,:],  idx = X[b,i]
// Linear-output mapping: thread t owns output float4 #t (perfect store
// coalescing, columns naturally interleaved in time). Per-lane column decode
// via compare chains (VALU-cheap); table pointers via cndmask select chain.
// Native ext_vector float4 (f4) so nontemporal builtins accept it.

constexpr int BATCH = 16384;
constexpr int NCOLS = 8;
constexpr int QUADS_PER_ROW = 62;                        // 248 floats / 4
constexpr unsigned TOTAL_QUADS = BATCH * QUADS_PER_ROW;  // 1,015,808
constexpr int TOTAL_BLOCKS = TOTAL_QUADS / 256;          // 3968 (exact)

typedef float f4 __attribute__((ext_vector_type(4)));

struct Params {
    const float* mu[NCOLS];
    const float* rho[NCOLS];
    const float* eps[NCOLS];
    const int*   X;     // [BATCH, 8] int32
    float*       out;   // [BATCH, 248] f32
};

__device__ __forceinline__ float softplus_f(float x) {
    // jax.nn.softplus = log1p(exp(x)); rho ~ N(-6,0.1), guard for exactness.
    return (x > 15.0f) ? x : log1pf(__expf(x));
}

__global__ __launch_bounds__(256) void bayes_embed_lin(Params p) {
    const unsigned t = blockIdx.x * 256u + threadIdx.x;  // global output quad id
    // b = t / 62 exactly for t < 2^21 (magic: ceil(2^37/62))
    const unsigned b = __umulhi(t, 2216757315u) >> 5;
    const unsigned q = t - b * 62u;                      // quad within row, 0..61

    // column quad boundaries: {0,16,32,40,48,52,56,60}
    const int ge16 = q >= 16, ge32 = q >= 32, ge40 = q >= 40, ge48 = q >= 48,
              ge52 = q >= 52, ge56 = q >= 56, ge60 = q >= 60;
    const int col = ge16 + ge32 + ge40 + ge48 + ge52 + ge56 + ge60;
    const unsigned qstart = ge60 ? 60u : ge56 ? 56u : ge52 ? 52u : ge48 ? 48u :
                            ge40 ? 40u : ge32 ? 32u : ge16 ? 16u : 0u;
    const int dshift = 4 - (ge32 + ge48 + ge60);         // log2(quads per table row)
    const unsigned d4 = q - qstart;                      // quad within table row

    const int idx = p.X[b * NCOLS + col];

    // register select chain (keeps pointer array out of scratch)
    const float* mu  = p.mu[0];
    const float* rho = p.rho[0];
    const float* eps = p.eps[0];
#pragma unroll
    for (int c = 1; c < NCOLS; ++c) {
        if (col == c) { mu = p.mu[c]; rho = p.rho[c]; eps = p.eps[c]; }
    }

    // 32-bit element offsets: max = 1e6 * 64 = 6.4e7 << 2^31
    const unsigned base = ((unsigned)idx << (dshift + 2)) + (d4 << 2);
    const f4 m = *(const f4*)(mu  + base);
    const f4 r = *(const f4*)(rho + base);
    const f4 e = *(const f4*)(eps + base);

    f4 o;
    o.x = m.x + softplus_f(r.x) * e.x;
    o.y = m.y + softplus_f(r.y) * e.y;
    o.z = m.z + softplus_f(r.z) * e.z;
    o.w = m.w + softplus_f(r.w) * e.w;

    // write-once output: nontemporal so it doesn't evict reusable table lines
    __builtin_nontemporal_store(o, (f4*)(p.out + (size_t)t * 4u));
}

extern "C" void kernel_launch(void* const* d_in, const int* in_sizes, int n_in,
                              void* d_out, int out_size, void* d_ws, size_t ws_size,
                              hipStream_t stream) {
    Params p;
    for (int i = 0; i < NCOLS; ++i) {
        p.mu[i]  = (const float*)d_in[3 * i + 0];
        p.rho[i] = (const float*)d_in[3 * i + 1];
        p.eps[i] = (const float*)d_in[3 * i + 2];
    }
    p.X   = (const int*)d_in[24];
    p.out = (float*)d_out;

    bayes_embed_lin<<<dim3(TOTAL_BLOCKS), 256, 0, stream>>>(p);
}